// Round 16
// baseline (22660.565 us; speedup 1.0000x reference)
//
#include <hip/hip_runtime.h>
#include <hip/hip_bf16.h>
#include <hip/hip_fp16.h>

// Decoder: 128-step GRU + Luong attention, B=64, H=1024. Persistent kernel,
// 256 WGs x 1024 thr, 3 grid barriers/step + 3 small handshakes, 4 phases.
// NUMERICS: weights bf16 3-way splits + 6-pass MFMA (2^-27, frozen); fp32
// state; o_enc fp16 hi (LDS-resident) + fp16 lo*2048 streamed (2^-22).
// ROUND 16:
//  - gemm6: 3-stage register pipeline (loads 3 k-iters ahead, ~100 VGPR).
//  - PH3 value pass: own-rows partials from LDS hi + L2-hot lo, exchanged
//    via a second 4-WG handshake; softmax via (max,sumexp) scalar exchange.
//    Deletes scattered HBM hi-reads + ballot machinery.
// Everything else identical to round 15 (21.1 ms best).

#define NWG 256
#define NTHR 1024
constexpr int BB = 64, TD = 128, TE = 256, HH = 1024, H3 = 3072;
constexpr unsigned SMEM_BYTES = 152576;

typedef __attribute__((ext_vector_type(8))) __bf16 bf16x8;
typedef __attribute__((ext_vector_type(4))) float f32x4;
typedef __attribute__((ext_vector_type(4))) _Float16 f16x4;
using bf = __hip_bfloat16;
using hf = _Float16;

__device__ __forceinline__ f32x4 mfma16(bf16x8 a, bf16x8 b, f32x4 c) {
  return __builtin_amdgcn_mfma_f32_16x16x32_bf16(a, b, c, 0, 0, 0);
}

struct Args {
  const float *x, *bfeed, *bxi, *bhr, *batt;
  const hf *ohi, *olo;
  const bf *Wf0, *Wf1, *Wf2, *Wh0, *Wh1, *Wh2;
  const bf *WxF0, *WxF1, *WxF2, *WxX0, *WxX1, *WxX2, *Wa0, *Wa1, *Wa2;
  float *h_f32;          // 2 planes ping-pong
  float *gx;             // 64 x 3072
  float *gh;
  float *mS;             // (b,q) -> {max, sumexp}  (256*2 floats)
  float *vpart;          // (b,q) -> partial value[1024]  (1MB)
  bf *hs0, *hs1, *hs2, *ff0, *ff1, *ff2, *ifd0, *ifd1, *ifd2;
  bf *xt0, *xt1, *xt2, *vl0, *vl1, *vl2;
  unsigned *cnt, *cnt2, *go, *gox, *ffc, *ffx, *afl1, *afl2;
  float *out;
};

// Hierarchical grid barrier (r14): 2-level arrive; release root->8 XCD lines.
__device__ __forceinline__ void gbar(unsigned ep, const Args& a, int wg) {
  __syncthreads();
  if (threadIdx.x == 0) {
    __threadfence();
    unsigned* sub = a.cnt + (wg & 15) * 32;
    unsigned o = __hip_atomic_fetch_add(sub, 1u, __ATOMIC_ACQ_REL, __HIP_MEMORY_SCOPE_AGENT);
    if (o == 15) {
      __hip_atomic_store(sub, 0u, __ATOMIC_RELAXED, __HIP_MEMORY_SCOPE_AGENT);
      unsigned o2 = __hip_atomic_fetch_add(a.cnt2, 1u, __ATOMIC_ACQ_REL, __HIP_MEMORY_SCOPE_AGENT);
      if (o2 == 15) {
        __hip_atomic_store(a.cnt2, 0u, __ATOMIC_RELAXED, __HIP_MEMORY_SCOPE_AGENT);
        __hip_atomic_store(a.go, ep, __ATOMIC_RELEASE, __HIP_MEMORY_SCOPE_AGENT);
      }
    }
    if (wg < 8) {
      while (__hip_atomic_load(a.go, __ATOMIC_RELAXED, __HIP_MEMORY_SCOPE_AGENT) < ep)
        __builtin_amdgcn_s_sleep(1);
      __hip_atomic_store(a.gox + wg * 32, ep, __ATOMIC_RELEASE, __HIP_MEMORY_SCOPE_AGENT);
    } else {
      while (__hip_atomic_load(a.gox + (wg & 7) * 32, __ATOMIC_RELAXED,
                               __HIP_MEMORY_SCOPE_AGENT) < ep)
        __builtin_amdgcn_s_sleep(1);
    }
    __threadfence();
  }
  __syncthreads();
}

// 4-WG quartet handshake on flag array fl (monotonic t+1), tid==0 only.
__device__ __forceinline__ void quartet_sync(unsigned* fl, int b, int q, unsigned tgt) {
  __threadfence();
  __hip_atomic_store(&fl[b * 4 + q], tgt, __ATOMIC_RELEASE, __HIP_MEMORY_SCOPE_AGENT);
  for (int p = 1; p < 4; ++p) {
    unsigned idx = b * 4 + ((q + p) & 3);
    while (__hip_atomic_load(&fl[idx], __ATOMIC_RELAXED, __HIP_MEMORY_SCOPE_AGENT) < tgt)
      __builtin_amdgcn_s_sleep(1);
  }
  __threadfence();
}

__device__ __forceinline__ void split3_write(bf* p0, bf* p1, bf* p2, size_t i, float v) {
  bf b0 = __float2bfloat16(v);
  float r1 = v - __bfloat162float(b0);
  bf b1 = __float2bfloat16(r1);
  float r2 = r1 - __bfloat162float(b1);
  p0[i] = b0; p1[i] = b1; p2[i] = __float2bfloat16(r2);
}

// 3-stage register-pipelined 6-pass split GEMM (loads 3 iters ahead; MFMA
// order identical to the proven gemm6 -> bit-identical results).
template <int K>
__device__ __forceinline__ f32x4 gemm6(const bf* A0, const bf* A1, const bf* A2,
                                       const bf* B0, const bf* B1, const bf* B2) {
  f32x4 c0 = {0.f, 0.f, 0.f, 0.f}, c1 = c0, c2 = c0, c3 = c0;
  bf16x8 a0 = *(const bf16x8*)(A0);
  bf16x8 a1 = *(const bf16x8*)(A1);
  bf16x8 a2 = *(const bf16x8*)(A2);
  bf16x8 b0 = *(const bf16x8*)(B0);
  bf16x8 b1 = *(const bf16x8*)(B1);
  bf16x8 b2 = *(const bf16x8*)(B2);
  bf16x8 xa0 = *(const bf16x8*)(A0 + 32);
  bf16x8 xa1 = *(const bf16x8*)(A1 + 32);
  bf16x8 xa2 = *(const bf16x8*)(A2 + 32);
  bf16x8 xb0 = *(const bf16x8*)(B0 + 32);
  bf16x8 xb1 = *(const bf16x8*)(B1 + 32);
  bf16x8 xb2 = *(const bf16x8*)(B2 + 32);
  bf16x8 ya0 = *(const bf16x8*)(A0 + 64);
  bf16x8 ya1 = *(const bf16x8*)(A1 + 64);
  bf16x8 ya2 = *(const bf16x8*)(A2 + 64);
  bf16x8 yb0 = *(const bf16x8*)(B0 + 64);
  bf16x8 yb1 = *(const bf16x8*)(B1 + 64);
  bf16x8 yb2 = *(const bf16x8*)(B2 + 64);
#pragma unroll
  for (int k = 0; k < K; k += 32) {
    bf16x8 n0, n1, n2, n3, n4, n5;
    if (k + 96 < K) {
      n0 = *(const bf16x8*)(A0 + k + 96);
      n1 = *(const bf16x8*)(A1 + k + 96);
      n2 = *(const bf16x8*)(A2 + k + 96);
      n3 = *(const bf16x8*)(B0 + k + 96);
      n4 = *(const bf16x8*)(B1 + k + 96);
      n5 = *(const bf16x8*)(B2 + k + 96);
    }
    c0 = mfma16(a0, b0, c0);
    c1 = mfma16(a0, b1, c1);
    c2 = mfma16(a1, b0, c2);
    c3 = mfma16(a1, b1, c3);
    c0 = mfma16(a0, b2, c0);
    c1 = mfma16(a2, b0, c1);
    a0 = xa0; a1 = xa1; a2 = xa2; b0 = xb0; b1 = xb1; b2 = xb2;
    xa0 = ya0; xa1 = ya1; xa2 = ya2; xb0 = yb0; xb1 = yb1; xb2 = yb2;
    if (k + 96 < K) {
      ya0 = n0; ya1 = n1; ya2 = n2; yb0 = n3; yb1 = n4; yb2 = n5;
    }
  }
  f32x4 s;
#pragma unroll
  for (int i = 0; i < 4; ++i) s[i] = (c0[i] + c1[i]) + (c2[i] + c3[i]);
  return s;
}

__global__ __launch_bounds__(NTHR, 4) void decoder_main(Args a) {
  const int wg = blockIdx.x;
  const int tid = threadIdx.x;
  const int lane = tid & 63;
  const int wv = tid >> 6;       // wave 0..15
  const int lrow = lane & 15;
  const int lkg = lane >> 4;

  extern __shared__ char smem[];
  hf* o_hi     = (hf*)smem;                    // [64][1024] fp16 = 131072 B
  float* s_u   = (float*)(smem + 131072);      // 4096 f
  float* s_h   = (float*)(smem + 147456);      // 1024 f
  float* s_sm  = (float*)(smem + 151552);      // 64 f (local scores -> weights)

  const int b3 = wg & 63, q3 = wg >> 6;   // PH3 identity (fixed all steps)
  // Prolog: load this WG's 64 score rows' hi-plane into LDS (once).
  {
    const ushort* src = (const ushort*)(a.ohi + ((size_t)b3 * TE + q3 * 64) * HH);
    ushort* dst = (ushort*)o_hi;
#pragma unroll 4
    for (int i = tid; i < 16384; i += NTHR)
      ((ushort4*)dst)[i] = ((const ushort4*)src)[i];
  }

  unsigned ep = 0;

  for (int t = 0; t < TD; ++t) {
    // ===== Phase I: ffeed (WGs 0..63) || gh (WGs 64..255); producer counter =====
    {
      const bool isf = (wg < 64);
      const int j0 = (isf ? wg : wg - 64) * 16;
      const bf* A0 = isf ? a.ifd0 : a.hs0;
      const bf* A1 = isf ? a.ifd1 : a.hs1;
      const bf* A2 = isf ? a.ifd2 : a.hs2;
      const bf* B0 = isf ? a.Wf0 : a.Wh0;
      const bf* B1 = isf ? a.Wf1 : a.Wh1;
      const bf* B2 = isf ? a.Wf2 : a.Wh2;
      const int mt = wv >> 2, kq = wv & 3;
      const size_t aoff = (size_t)(mt * 16 + lrow) * HH + kq * 256 + lkg * 8;
      const size_t boff = (size_t)(j0 + lrow) * HH + kq * 256 + lkg * 8;
      f32x4 acc = gemm6<256>(A0 + aoff, A1 + aoff, A2 + aoff, B0 + boff, B1 + boff, B2 + boff);
#pragma unroll
      for (int r = 0; r < 4; ++r) s_u[kq * 1024 + mt * 256 + (lkg * 4 + r) * 16 + lrow] = acc[r];
      __syncthreads();
      {
        const int row = tid >> 4, c = tid & 15;
        const int emt = row >> 4, r2 = row & 15;
        const int e = emt * 256 + r2 * 16 + c;
        float v = (s_u[e] + s_u[1024 + e]) + (s_u[2048 + e] + s_u[3072 + e]);
        const int col = j0 + c;
        if (isf) {
          float f = tanhf(v + a.bfeed[col]);
          split3_write(a.ff0, a.ff1, a.ff2, (size_t)row * HH + col, f);
        } else {
          a.gh[(size_t)row * H3 + col] = v + a.bhr[col];
        }
      }
      __syncthreads();
      if (isf && tid == 0) {
        __threadfence();
        __hip_atomic_fetch_add(a.ffc, 1u, __ATOMIC_ACQ_REL, __HIP_MEMORY_SCOPE_AGENT);
      }
    }
    if (tid == 0) {
      const unsigned tgt = 64u * (unsigned)(t + 1);
      if (wg < 8) {
        while (__hip_atomic_load(a.ffc, __ATOMIC_RELAXED, __HIP_MEMORY_SCOPE_AGENT) < tgt)
          __builtin_amdgcn_s_sleep(1);
        __hip_atomic_store(a.ffx + wg * 32, tgt, __ATOMIC_RELEASE, __HIP_MEMORY_SCOPE_AGENT);
      } else {
        while (__hip_atomic_load(a.ffx + (wg & 7) * 32, __ATOMIC_RELAXED,
                                 __HIP_MEMORY_SCOPE_AGENT) < tgt)
          __builtin_amdgcn_s_sleep(1);
      }
      __threadfence();
    }
    __syncthreads();

    // ===== Phase II: gx; r12 layout (XCD-aware (jt,sub), 12 waves) =====
    {
      const int xcd = wg & 7, slot = wg >> 3;
      const int jt = xcd * 8 + (slot >> 2), sub = slot & 3;
      if (wv < 12) {
        const int ci = wv >> 2, ku = wv & 3;
        const int c2 = sub * 3 + ci;
        const int g = c2 >> 2, mt = c2 & 3;
        const int op = ku >> 1, kh = ku & 1;
        const bf* A0 = op ? a.xt0 : a.ff0;
        const bf* A1 = op ? a.xt1 : a.ff1;
        const bf* A2 = op ? a.xt2 : a.ff2;
        const bf* B0 = op ? a.WxX0 : a.WxF0;
        const bf* B1 = op ? a.WxX1 : a.WxF1;
        const bf* B2 = op ? a.WxX2 : a.WxF2;
        const size_t aoff = (size_t)(mt * 16 + lrow) * HH + kh * 512 + lkg * 8;
        const size_t boff = (size_t)(g * HH + jt * 16 + lrow) * HH + kh * 512 + lkg * 8;
        f32x4 acc = gemm6<512>(A0 + aoff, A1 + aoff, A2 + aoff, B0 + boff, B1 + boff, B2 + boff);
#pragma unroll
        for (int r = 0; r < 4; ++r)
          s_u[ci * 1024 + ku * 256 + (lkg * 4 + r) * 16 + lrow] = acc[r];
      }
      __syncthreads();
      if (tid < 768) {
        const int ci2 = tid >> 8, e = tid & 255;
        const int r16 = e >> 4, c16 = e & 15;
        const int base = ci2 * 1024 + e;
        float v = (s_u[base] + s_u[base + 256]) + (s_u[base + 512] + s_u[base + 768]);
        const int c2 = sub * 3 + ci2;
        const int g = c2 >> 2, mt = c2 & 3;
        a.gx[(size_t)(mt * 16 + r16) * H3 + g * 1024 + jt * 16 + c16] = v;
      }
    }
    gbar(++ep, a, wg);

    // ===== PH3: GRU pointwise + local scores + scalar-softmax exchange +
    //            own-rows value partials (LDS hi + L2-hot lo) + exchange =====
    {
      const int b = b3, q = q3;
      const float* hold = a.h_f32 + (size_t)(t & 1) * (BB * HH);
      float* hnew = a.h_f32 + (size_t)((t + 1) & 1) * (BB * HH);
      const float* ghb = a.gh + (size_t)b * H3;
      {
        const int col = tid;
        const float* gxb = a.gx + (size_t)b * H3;
        float gz = a.bxi[col] + gxb[col];
        float gr = a.bxi[HH + col] + gxb[HH + col];
        float gc = a.bxi[2 * HH + col] + gxb[2 * HH + col];
        float z = 1.f / (1.f + expf(-(gz + ghb[col])));
        float rr = 1.f / (1.f + expf(-(gr + ghb[HH + col])));
        float hc = tanhf(gc + rr * ghb[2 * HH + col]);
        float hn = z * hold[(size_t)b * HH + col] + (1.f - z) * hc;
        s_h[col] = hn;
        if (q == 0) {
          hnew[(size_t)b * HH + col] = hn;
          split3_write(a.hs0, a.hs1, a.hs2, (size_t)b * HH + col, hn);
        }
      }
      __syncthreads();
      // scores for own 64 rows -> s_sm (LDS hi + streamed lo, 2-deep pipelined)
      {
        f32x4 sh0 = *(const f32x4*)(s_h + 0 + lane * 4);
        f32x4 sh1 = *(const f32x4*)(s_h + 256 + lane * 4);
        f32x4 sh2 = *(const f32x4*)(s_h + 512 + lane * 4);
        f32x4 sh3 = *(const f32x4*)(s_h + 768 + lane * 4);
        const hf* lobase = a.olo + ((size_t)b * TE + q * 64 + wv * 4) * HH + lane * 4;
        f16x4 l0 = *(const f16x4*)(lobase);
        f16x4 l1 = *(const f16x4*)(lobase + 256);
        f16x4 l2 = *(const f16x4*)(lobase + 512);
        f16x4 l3 = *(const f16x4*)(lobase + 768);
#pragma unroll
        for (int i = 0; i < 4; ++i) {
          f16x4 n0, n1, n2, n3;
          if (i + 1 < 4) {
            const hf* nr = lobase + (size_t)(i + 1) * HH;
            n0 = *(const f16x4*)(nr);
            n1 = *(const f16x4*)(nr + 256);
            n2 = *(const f16x4*)(nr + 512);
            n3 = *(const f16x4*)(nr + 768);
          }
          const hf* hrow = o_hi + (size_t)(wv * 4 + i) * HH + lane * 4;
          f16x4 h0 = *(const f16x4*)(hrow);
          f16x4 h1 = *(const f16x4*)(hrow + 256);
          f16x4 h2 = *(const f16x4*)(hrow + 512);
          f16x4 h3 = *(const f16x4*)(hrow + 768);
          float shi = (float)h0[0] * sh0[0] + (float)h0[1] * sh0[1] + (float)h0[2] * sh0[2] + (float)h0[3] * sh0[3]
                    + (float)h1[0] * sh1[0] + (float)h1[1] * sh1[1] + (float)h1[2] * sh1[2] + (float)h1[3] * sh1[3]
                    + (float)h2[0] * sh2[0] + (float)h2[1] * sh2[1] + (float)h2[2] * sh2[2] + (float)h2[3] * sh2[3]
                    + (float)h3[0] * sh3[0] + (float)h3[1] * sh3[1] + (float)h3[2] * sh3[2] + (float)h3[3] * sh3[3];
          float slo = (float)l0[0] * sh0[0] + (float)l0[1] * sh0[1] + (float)l0[2] * sh0[2] + (float)l0[3] * sh0[3]
                    + (float)l1[0] * sh1[0] + (float)l1[1] * sh1[1] + (float)l1[2] * sh1[2] + (float)l1[3] * sh1[3]
                    + (float)l2[0] * sh2[0] + (float)l2[1] * sh2[1] + (float)l2[2] * sh2[2] + (float)l2[3] * sh2[3]
                    + (float)l3[0] * sh3[0] + (float)l3[1] * sh3[1] + (float)l3[2] * sh3[2] + (float)l3[3] * sh3[3];
          float s = shi + slo * (1.0f / 2048.0f);
          for (int off = 32; off; off >>= 1) s += __shfl_xor(s, off);
          if (lane == 0) s_sm[wv * 4 + i] = s;
          l0 = n0; l1 = n1; l2 = n2; l3 = n3;
        }
      }
      __syncthreads();
      // local (max, sumexp) over own 64 scores; publish scalars
      if (tid < 64) {
        float v = s_sm[tid];
        float m = v;
        for (int off = 32; off; off >>= 1) m = fmaxf(m, __shfl_xor(m, off));
        float e2 = expf(v - m);
        float S = e2;
        for (int off = 32; off; off >>= 1) S += __shfl_xor(S, off);
        if (tid == 0) {
          a.mS[(b * 4 + q) * 2]     = m;
          a.mS[(b * 4 + q) * 2 + 1] = S;
        }
      }
      __syncthreads();
      if (tid == 0) quartet_sync(a.afl1, b, q, (unsigned)(t + 1));
      __syncthreads();
      // global softmax weights for own rows
      if (tid < 64) {
        float m0 = a.mS[(b * 4 + 0) * 2], S0 = a.mS[(b * 4 + 0) * 2 + 1];
        float m1 = a.mS[(b * 4 + 1) * 2], S1 = a.mS[(b * 4 + 1) * 2 + 1];
        float m2 = a.mS[(b * 4 + 2) * 2], S2 = a.mS[(b * 4 + 2) * 2 + 1];
        float m3 = a.mS[(b * 4 + 3) * 2], S3 = a.mS[(b * 4 + 3) * 2 + 1];
        float M = fmaxf(fmaxf(m0, m1), fmaxf(m2, m3));
        float den = S0 * expf(m0 - M) + S1 * expf(m1 - M) +
                    S2 * expf(m2 - M) + S3 * expf(m3 - M);
        s_sm[tid] = expf(s_sm[tid] - M) / den;
      }
      __syncthreads();
      // value partial over own rows (uniform skip); hi from LDS, lo L2-hot
      {
        float accv = 0.f;
        const hf* lob = a.olo + ((size_t)b * TE + q * 64) * HH + tid;
        for (int r = 0; r < 64; ++r) {
          float w = s_sm[r];
          if (w > 1e-8f) {
            float hi = (float)o_hi[(size_t)r * HH + tid];
            float lo = (float)lob[(size_t)r * HH];
            accv += w * (hi + lo * (1.0f / 2048.0f));
          }
        }
        a.vpart[(size_t)(b * 4 + q) * HH + tid] = accv;
      }
      __syncthreads();
      if (tid == 0) quartet_sync(a.afl2, b, q, (unsigned)(t + 1));
      __syncthreads();
      if (tid < 256) {
        const int col = q * 256 + tid;
        float v = (a.vpart[(size_t)(b * 4 + 0) * HH + col] +
                   a.vpart[(size_t)(b * 4 + 1) * HH + col]) +
                  (a.vpart[(size_t)(b * 4 + 2) * HH + col] +
                   a.vpart[(size_t)(b * 4 + 3) * HH + col]);
        split3_write(a.vl0, a.vl1, a.vl2, (size_t)b * HH + col, v);
      }
    }
    gbar(++ep, a, wg);

    // ===== PH4: att GEMM full-K in-WG; LDS reduce -> out/ifd; stage x_{t+1} =====
    {
      const int cu = wg & 63;
      const int mt = wg >> 6;
      const int kq16 = wv;
      const bool isv = (kq16 < 8);
      const int koff = (kq16 & 7) * 128;
      const bf* A0 = isv ? a.vl0 : a.hs0;
      const bf* A1 = isv ? a.vl1 : a.hs1;
      const bf* A2 = isv ? a.vl2 : a.hs2;
      const size_t aoff = (size_t)(mt * 16 + lrow) * HH + koff + lkg * 8;
      const size_t boff = (size_t)(cu * 16 + lrow) * 2048 + kq16 * 128 + lkg * 8;
      f32x4 acc = gemm6<128>(A0 + aoff, A1 + aoff, A2 + aoff,
                             a.Wa0 + boff, a.Wa1 + boff, a.Wa2 + boff);
#pragma unroll
      for (int r = 0; r < 4; ++r)
        s_u[kq16 * 256 + (lkg * 4 + r) * 16 + lrow] = acc[r];
      __syncthreads();
      if (tid < 256) {
        const int r16 = tid >> 4, c16 = tid & 15;
        const int e = r16 * 16 + c16;
        float v = a.batt[cu * 16 + c16];
#pragma unroll
        for (int kq = 0; kq < 16; ++kq) v += s_u[kq * 256 + e];
        float hv = tanhf(v);
        const int row = mt * 16 + r16;
        const int col = cu * 16 + c16;
        a.out[((size_t)row * TD + t) * HH + col] = hv;
        split3_write(a.ifd0, a.ifd1, a.ifd2, (size_t)row * HH + col, hv);
      }
      if (wg < 64 && t + 1 < TD) {
        split3_write(a.xt0, a.xt1, a.xt2, (size_t)wg * HH + tid,
                     a.x[((size_t)wg * TD + (t + 1)) * HH + tid]);
      }
    }
    gbar(++ep, a, wg);
  }
}

// -------- prep kernels --------
__global__ void k_tr3(const float* src, bf* d0, bf* d1, bf* d2, int R, int C) {
  __shared__ float tile[32][33];
  int c0 = blockIdx.x * 32, r0 = blockIdx.y * 32;
  int tx = threadIdx.x & 31, ty = threadIdx.x >> 5;
  for (int i = ty; i < 32; i += 8)
    tile[i][tx] = src[(size_t)(r0 + i) * C + c0 + tx];
  __syncthreads();
  for (int i = ty; i < 32; i += 8) {
    float v = tile[tx][i];
    size_t o = (size_t)(c0 + i) * R + r0 + tx;
    bf b0 = __float2bfloat16(v);
    float r1 = v - __bfloat162float(b0);
    bf b1 = __float2bfloat16(r1);
    d0[o] = b0; d1[o] = b1; d2[o] = __float2bfloat16(r1 - __bfloat162float(b1));
  }
}

__global__ void k_osplit(const float* src, hf* dhi, hf* dlo) {
  size_t i = (size_t)blockIdx.x * blockDim.x + threadIdx.x;
  float v = src[i];
  hf h = (hf)v;
  dhi[i] = h;
  dlo[i] = (hf)((v - (float)h) * 2048.0f);
}

__global__ void k_init(const float* h_enc, float* h_f32, bf* h0, bf* h1, bf* h2,
                       bf* i0, bf* i1, bf* i2, const float* x, bf* x0, bf* x1, bf* x2) {
  int i = blockIdx.x * blockDim.x + threadIdx.x;
  float v = h_enc[i];
  h_f32[i] = v;
  split3_write(h0, h1, h2, i, v);
  bf z = __float2bfloat16(0.f);
  i0[i] = z; i1[i] = z; i2[i] = z;
  int row = i >> 10, col = i & 1023;
  split3_write(x0, x1, x2, i, x[((size_t)row * TD + 0) * HH + col]);
}

extern "C" void kernel_launch(void* const* d_in, const int* in_sizes, int n_in,
                              void* d_out, int out_size, void* d_ws, size_t ws_size,
                              hipStream_t stream) {
  const float* x     = (const float*)d_in[0];
  const float* o_enc = (const float*)d_in[1];
  const float* h_enc = (const float*)d_in[2];
  const float* Wfeed = (const float*)d_in[3];
  const float* bfeed = (const float*)d_in[4];
  const float* Wx    = (const float*)d_in[5];
  const float* Wh    = (const float*)d_in[6];
  const float* bxi   = (const float*)d_in[7];
  const float* bhr   = (const float*)d_in[8];
  const float* Watt  = (const float*)d_in[9];
  const float* batt  = (const float*)d_in[10];

  char* w = (char*)d_ws;
  auto alloc = [&](size_t b) { char* p = w; w += (b + 255) & ~255ULL; return p; };

  const size_t M1 = (size_t)1024 * 1024 * 2;
  bf* Wf[3];  for (auto& p : Wf)  p = (bf*)alloc(M1);
  bf* Wh_[3]; for (auto& p : Wh_) p = (bf*)alloc(3 * M1);
  bf* WxF[3]; for (auto& p : WxF) p = (bf*)alloc(3 * M1);
  bf* WxX[3]; for (auto& p : WxX) p = (bf*)alloc(3 * M1);
  bf* Wa[3];  for (auto& p : Wa)  p = (bf*)alloc(2 * M1);
  hf* ohi = (hf*)alloc((size_t)BB * TE * HH * 2);
  hf* olo = (hf*)alloc((size_t)BB * TE * HH * 2);
  float* h_f32 = (float*)alloc((size_t)2 * BB * HH * 4);
  float* gx    = (float*)alloc((size_t)BB * H3 * 4);
  float* gh    = (float*)alloc((size_t)BB * H3 * 4);
  float* mS    = (float*)alloc(256 * 2 * 4);
  float* vpart = (float*)alloc((size_t)256 * HH * 4);
  const size_t AB = (size_t)BB * HH * 2;
  bf *hs[3], *ff[3], *ifd[3], *xt[3], *vl[3];
  for (auto& p : hs)  p = (bf*)alloc(AB);
  for (auto& p : ff)  p = (bf*)alloc(AB);
  for (auto& p : ifd) p = (bf*)alloc(AB);
  for (auto& p : xt)  p = (bf*)alloc(AB);
  for (auto& p : vl)  p = (bf*)alloc(AB);
  unsigned* flags = (unsigned*)alloc(16384);

  hipMemsetAsync(flags, 0, 16384, stream);
  k_tr3<<<dim3(32, 32), 256, 0, stream>>>(Wfeed, Wf[0], Wf[1], Wf[2], 1024, 1024);
  k_tr3<<<dim3(96, 32), 256, 0, stream>>>(Wx, WxF[0], WxF[1], WxF[2], 1024, 3072);
  k_tr3<<<dim3(96, 32), 256, 0, stream>>>(Wx + (size_t)1024 * 3072, WxX[0], WxX[1], WxX[2], 1024, 3072);
  k_tr3<<<dim3(96, 32), 256, 0, stream>>>(Wh, Wh_[0], Wh_[1], Wh_[2], 1024, 3072);
  k_tr3<<<dim3(32, 64), 256, 0, stream>>>(Watt, Wa[0], Wa[1], Wa[2], 2048, 1024);
  k_osplit<<<(BB * TE * HH) / 256, 256, 0, stream>>>(o_enc, ohi, olo);
  k_init<<<BB * HH / 256, 256, 0, stream>>>(h_enc, h_f32, hs[0], hs[1], hs[2],
                                            ifd[0], ifd[1], ifd[2], x, xt[0], xt[1], xt[2]);

  Args a;
  a.x = x; a.bfeed = bfeed; a.bxi = bxi; a.bhr = bhr; a.batt = batt;
  a.ohi = ohi; a.olo = olo;
  a.Wf0 = Wf[0]; a.Wf1 = Wf[1]; a.Wf2 = Wf[2];
  a.Wh0 = Wh_[0]; a.Wh1 = Wh_[1]; a.Wh2 = Wh_[2];
  a.WxF0 = WxF[0]; a.WxF1 = WxF[1]; a.WxF2 = WxF[2];
  a.WxX0 = WxX[0]; a.WxX1 = WxX[1]; a.WxX2 = WxX[2];
  a.Wa0 = Wa[0]; a.Wa1 = Wa[1]; a.Wa2 = Wa[2];
  a.h_f32 = h_f32; a.gx = gx; a.gh = gh; a.mS = mS; a.vpart = vpart;
  a.hs0 = hs[0]; a.hs1 = hs[1]; a.hs2 = hs[2];
  a.ff0 = ff[0]; a.ff1 = ff[1]; a.ff2 = ff[2];
  a.ifd0 = ifd[0]; a.ifd1 = ifd[1]; a.ifd2 = ifd[2];
  a.xt0 = xt[0]; a.xt1 = xt[1]; a.xt2 = xt[2];
  a.vl0 = vl[0]; a.vl1 = vl[1]; a.vl2 = vl[2];
  a.cnt = flags;            // 512 u
  a.cnt2 = flags + 512;
  a.go = flags + 544;
  a.gox = flags + 576;      // 8*32
  a.ffc = flags + 832;
  a.ffx = flags + 864;      // 8*32
  a.afl1 = flags + 1152;    // 256
  a.afl2 = flags + 1408;    // 256
  a.out = (float*)d_out;

  hipFuncSetAttribute((const void*)decoder_main,
                      hipFuncAttributeMaxDynamicSharedMemorySize, SMEM_BYTES);
  decoder_main<<<NWG, NTHR, SMEM_BYTES, stream>>>(a);
}

// Round 17
// 21361.717 us; speedup vs baseline: 1.0608x; 1.0608x over previous
//
#include <hip/hip_runtime.h>
#include <hip/hip_bf16.h>
#include <hip/hip_fp16.h>

// Decoder: 128-step GRU + Luong attention, B=64, H=1024. Persistent kernel,
// 256 WGs x 1024 thr, 2 grid barriers/step + producer flags, 4 phases.
// NUMERICS (= round 15, best 21.1ms, absmax 0.01367): weights bf16 3-way
// splits + 6-pass MFMA (2^-27); fp32 state; o_enc fp16 hi (LDS-resident) +
// fp16 lo*2048 streamed (2^-22); ballot-compacted sparse value.
// ROUND 17 = r15 + PH3->PH4 grid barrier replaced by per-batch producer
// counters (each PH3 quartet member releases vc[b]; PH4 polls its 16 batch
// counters to 4*(t+1)). Converts straggler-max over 256 WGs into 16 local
// polls; early consumers start PH4 before global completion. Math untouched.

#define NWG 256
#define NTHR 1024
constexpr int BB = 64, TD = 128, TE = 256, HH = 1024, H3 = 3072;
constexpr unsigned SMEM_BYTES = 155696;

typedef __attribute__((ext_vector_type(8))) __bf16 bf16x8;
typedef __attribute__((ext_vector_type(4))) float f32x4;
typedef __attribute__((ext_vector_type(4))) _Float16 f16x4;
using bf = __hip_bfloat16;
using hf = _Float16;

__device__ __forceinline__ f32x4 mfma16(bf16x8 a, bf16x8 b, f32x4 c) {
  return __builtin_amdgcn_mfma_f32_16x16x32_bf16(a, b, c, 0, 0, 0);
}

struct Args {
  const float *x, *bfeed, *bxi, *bhr, *batt;
  const hf *ohi, *olo;
  const bf *Wf0, *Wf1, *Wf2, *Wh0, *Wh1, *Wh2;
  const bf *WxF0, *WxF1, *WxF2, *WxX0, *WxX1, *WxX2, *Wa0, *Wa1, *Wa2;
  float *h_f32;          // 2 planes ping-pong
  float *gx;             // 64 x 3072
  float *gh, *scores;
  bf *hs0, *hs1, *hs2, *ff0, *ff1, *ff2, *ifd0, *ifd1, *ifd2;
  bf *xt0, *xt1, *xt2, *vl0, *vl1, *vl2;
  unsigned *cnt, *cnt2, *go, *afl, *gox, *ffc, *ffx, *vc;
  float *out;
};

// Hierarchical grid barrier (r14): 2-level arrive; release root->8 XCD lines.
__device__ __forceinline__ void gbar(unsigned ep, const Args& a, int wg) {
  __syncthreads();
  if (threadIdx.x == 0) {
    __threadfence();
    unsigned* sub = a.cnt + (wg & 15) * 32;
    unsigned o = __hip_atomic_fetch_add(sub, 1u, __ATOMIC_ACQ_REL, __HIP_MEMORY_SCOPE_AGENT);
    if (o == 15) {
      __hip_atomic_store(sub, 0u, __ATOMIC_RELAXED, __HIP_MEMORY_SCOPE_AGENT);
      unsigned o2 = __hip_atomic_fetch_add(a.cnt2, 1u, __ATOMIC_ACQ_REL, __HIP_MEMORY_SCOPE_AGENT);
      if (o2 == 15) {
        __hip_atomic_store(a.cnt2, 0u, __ATOMIC_RELAXED, __HIP_MEMORY_SCOPE_AGENT);
        __hip_atomic_store(a.go, ep, __ATOMIC_RELEASE, __HIP_MEMORY_SCOPE_AGENT);
      }
    }
    if (wg < 8) {
      while (__hip_atomic_load(a.go, __ATOMIC_RELAXED, __HIP_MEMORY_SCOPE_AGENT) < ep)
        __builtin_amdgcn_s_sleep(1);
      __hip_atomic_store(a.gox + wg * 32, ep, __ATOMIC_RELEASE, __HIP_MEMORY_SCOPE_AGENT);
    } else {
      while (__hip_atomic_load(a.gox + (wg & 7) * 32, __ATOMIC_RELAXED,
                               __HIP_MEMORY_SCOPE_AGENT) < ep)
        __builtin_amdgcn_s_sleep(1);
    }
    __threadfence();
  }
  __syncthreads();
}

__device__ __forceinline__ void split3_write(bf* p0, bf* p1, bf* p2, size_t i, float v) {
  bf b0 = __float2bfloat16(v);
  float r1 = v - __bfloat162float(b0);
  bf b1 = __float2bfloat16(r1);
  float r2 = r1 - __bfloat162float(b1);
  p0[i] = b0; p1[i] = b1; p2[i] = __float2bfloat16(r2);
}

// 2-stage register-pipelined 6-pass split GEMM (r13; MFMA order = proven gemm6).
template <int K>
__device__ __forceinline__ f32x4 gemm6(const bf* A0, const bf* A1, const bf* A2,
                                       const bf* B0, const bf* B1, const bf* B2) {
  f32x4 c0 = {0.f, 0.f, 0.f, 0.f}, c1 = c0, c2 = c0, c3 = c0;
  bf16x8 a0 = *(const bf16x8*)(A0);
  bf16x8 a1 = *(const bf16x8*)(A1);
  bf16x8 a2 = *(const bf16x8*)(A2);
  bf16x8 b0 = *(const bf16x8*)(B0);
  bf16x8 b1 = *(const bf16x8*)(B1);
  bf16x8 b2 = *(const bf16x8*)(B2);
#pragma unroll
  for (int k = 0; k < K; k += 32) {
    bf16x8 na0, na1, na2, nb0, nb1, nb2;
    if (k + 32 < K) {
      na0 = *(const bf16x8*)(A0 + k + 32);
      na1 = *(const bf16x8*)(A1 + k + 32);
      na2 = *(const bf16x8*)(A2 + k + 32);
      nb0 = *(const bf16x8*)(B0 + k + 32);
      nb1 = *(const bf16x8*)(B1 + k + 32);
      nb2 = *(const bf16x8*)(B2 + k + 32);
    }
    c0 = mfma16(a0, b0, c0);
    c1 = mfma16(a0, b1, c1);
    c2 = mfma16(a1, b0, c2);
    c3 = mfma16(a1, b1, c3);
    c0 = mfma16(a0, b2, c0);
    c1 = mfma16(a2, b0, c1);
    if (k + 32 < K) {
      a0 = na0; a1 = na1; a2 = na2;
      b0 = nb0; b1 = nb1; b2 = nb2;
    }
  }
  f32x4 s;
#pragma unroll
  for (int i = 0; i < 4; ++i) s[i] = (c0[i] + c1[i]) + (c2[i] + c3[i]);
  return s;
}

__global__ __launch_bounds__(NTHR, 4) void decoder_main(Args a) {
  const int wg = blockIdx.x;
  const int tid = threadIdx.x;
  const int lane = tid & 63;
  const int wv = tid >> 6;       // wave 0..15
  const int lrow = lane & 15;
  const int lkg = lane >> 4;

  extern __shared__ char smem[];
  hf* o_hi     = (hf*)smem;                    // [64][1024] fp16 = 131072 B
  float* s_u   = (float*)(smem + 131072);      // 4096 f
  float* s_h   = (float*)(smem + 147456);      // 1024 f
  float* s_sm  = (float*)(smem + 151552);      // 256 f
  float* s_val = (float*)(smem + 152576);      // [2][256] f
  int* s_idx   = (int*)(smem + 154624);        // 256 i
  int* s_wcnt  = (int*)(smem + 155648);        // 4 i
  float* s_red = (float*)(smem + 155664);      // 8 f

  const int b3 = wg & 63, q3 = wg >> 6;   // PH3 identity (fixed all steps)
  // Prolog: load this WG's 64 score rows' hi-plane into LDS (once).
  {
    const ushort* src = (const ushort*)(a.ohi + ((size_t)b3 * TE + q3 * 64) * HH);
    ushort* dst = (ushort*)o_hi;
#pragma unroll 4
    for (int i = tid; i < 16384; i += NTHR)
      ((ushort4*)dst)[i] = ((const ushort4*)src)[i];
  }

  unsigned ep = 0;

  for (int t = 0; t < TD; ++t) {
    // ===== Phase I: ffeed (WGs 0..63) || gh (WGs 64..255); producer counter =====
    {
      const bool isf = (wg < 64);
      const int j0 = (isf ? wg : wg - 64) * 16;
      const bf* A0 = isf ? a.ifd0 : a.hs0;
      const bf* A1 = isf ? a.ifd1 : a.hs1;
      const bf* A2 = isf ? a.ifd2 : a.hs2;
      const bf* B0 = isf ? a.Wf0 : a.Wh0;
      const bf* B1 = isf ? a.Wf1 : a.Wh1;
      const bf* B2 = isf ? a.Wf2 : a.Wh2;
      const int mt = wv >> 2, kq = wv & 3;
      const size_t aoff = (size_t)(mt * 16 + lrow) * HH + kq * 256 + lkg * 8;
      const size_t boff = (size_t)(j0 + lrow) * HH + kq * 256 + lkg * 8;
      f32x4 acc = gemm6<256>(A0 + aoff, A1 + aoff, A2 + aoff, B0 + boff, B1 + boff, B2 + boff);
#pragma unroll
      for (int r = 0; r < 4; ++r) s_u[kq * 1024 + mt * 256 + (lkg * 4 + r) * 16 + lrow] = acc[r];
      __syncthreads();
      {
        const int row = tid >> 4, c = tid & 15;
        const int emt = row >> 4, r2 = row & 15;
        const int e = emt * 256 + r2 * 16 + c;
        float v = (s_u[e] + s_u[1024 + e]) + (s_u[2048 + e] + s_u[3072 + e]);
        const int col = j0 + c;
        if (isf) {
          float f = tanhf(v + a.bfeed[col]);
          split3_write(a.ff0, a.ff1, a.ff2, (size_t)row * HH + col, f);
        } else {
          a.gh[(size_t)row * H3 + col] = v + a.bhr[col];
        }
      }
      __syncthreads();
      if (isf && tid == 0) {
        __threadfence();
        __hip_atomic_fetch_add(a.ffc, 1u, __ATOMIC_ACQ_REL, __HIP_MEMORY_SCOPE_AGENT);
      }
    }
    if (tid == 0) {
      const unsigned tgt = 64u * (unsigned)(t + 1);
      if (wg < 8) {
        while (__hip_atomic_load(a.ffc, __ATOMIC_RELAXED, __HIP_MEMORY_SCOPE_AGENT) < tgt)
          __builtin_amdgcn_s_sleep(1);
        __hip_atomic_store(a.ffx + wg * 32, tgt, __ATOMIC_RELEASE, __HIP_MEMORY_SCOPE_AGENT);
      } else {
        while (__hip_atomic_load(a.ffx + (wg & 7) * 32, __ATOMIC_RELAXED,
                                 __HIP_MEMORY_SCOPE_AGENT) < tgt)
          __builtin_amdgcn_s_sleep(1);
      }
      __threadfence();
    }
    __syncthreads();

    // ===== Phase II: gx; r12 layout (XCD-aware (jt,sub), 12 waves) =====
    {
      const int xcd = wg & 7, slot = wg >> 3;
      const int jt = xcd * 8 + (slot >> 2), sub = slot & 3;
      if (wv < 12) {
        const int ci = wv >> 2, ku = wv & 3;
        const int c2 = sub * 3 + ci;
        const int g = c2 >> 2, mt = c2 & 3;
        const int op = ku >> 1, kh = ku & 1;
        const bf* A0 = op ? a.xt0 : a.ff0;
        const bf* A1 = op ? a.xt1 : a.ff1;
        const bf* A2 = op ? a.xt2 : a.ff2;
        const bf* B0 = op ? a.WxX0 : a.WxF0;
        const bf* B1 = op ? a.WxX1 : a.WxF1;
        const bf* B2 = op ? a.WxX2 : a.WxF2;
        const size_t aoff = (size_t)(mt * 16 + lrow) * HH + kh * 512 + lkg * 8;
        const size_t boff = (size_t)(g * HH + jt * 16 + lrow) * HH + kh * 512 + lkg * 8;
        f32x4 acc = gemm6<512>(A0 + aoff, A1 + aoff, A2 + aoff, B0 + boff, B1 + boff, B2 + boff);
#pragma unroll
        for (int r = 0; r < 4; ++r)
          s_u[ci * 1024 + ku * 256 + (lkg * 4 + r) * 16 + lrow] = acc[r];
      }
      __syncthreads();
      if (tid < 768) {
        const int ci2 = tid >> 8, e = tid & 255;
        const int r16 = e >> 4, c16 = e & 15;
        const int base = ci2 * 1024 + e;
        float v = (s_u[base] + s_u[base + 256]) + (s_u[base + 512] + s_u[base + 768]);
        const int c2 = sub * 3 + ci2;
        const int g = c2 >> 2, mt = c2 & 3;
        a.gx[(size_t)(mt * 16 + r16) * H3 + g * 1024 + jt * 16 + c16] = v;
      }
    }
    gbar(++ep, a, wg);

    // ===== PH3: GRU pointwise + scores (LDS hi + streamed lo) + softmax + value =====
    {
      const int b = b3, q = q3;
      const float* hold = a.h_f32 + (size_t)(t & 1) * (BB * HH);
      float* hnew = a.h_f32 + (size_t)((t + 1) & 1) * (BB * HH);
      const float* ghb = a.gh + (size_t)b * H3;
      {
        const int col = tid;
        const float* gxb = a.gx + (size_t)b * H3;
        float gz = a.bxi[col] + gxb[col];
        float gr = a.bxi[HH + col] + gxb[HH + col];
        float gc = a.bxi[2 * HH + col] + gxb[2 * HH + col];
        float z = 1.f / (1.f + expf(-(gz + ghb[col])));
        float rr = 1.f / (1.f + expf(-(gr + ghb[HH + col])));
        float hc = tanhf(gc + rr * ghb[2 * HH + col]);
        float hn = z * hold[(size_t)b * HH + col] + (1.f - z) * hc;
        s_h[col] = hn;
        if (q == 0) {
          hnew[(size_t)b * HH + col] = hn;
          split3_write(a.hs0, a.hs1, a.hs2, (size_t)b * HH + col, hn);
        }
      }
      __syncthreads();
      // scores: hi from LDS, lo streamed (2-deep pipelined); 16 waves x 4 rows
      {
        f32x4 sh0 = *(const f32x4*)(s_h + 0 + lane * 4);
        f32x4 sh1 = *(const f32x4*)(s_h + 256 + lane * 4);
        f32x4 sh2 = *(const f32x4*)(s_h + 512 + lane * 4);
        f32x4 sh3 = *(const f32x4*)(s_h + 768 + lane * 4);
        const hf* lobase = a.olo + ((size_t)b * TE + q * 64 + wv * 4) * HH + lane * 4;
        f16x4 l0 = *(const f16x4*)(lobase);
        f16x4 l1 = *(const f16x4*)(lobase + 256);
        f16x4 l2 = *(const f16x4*)(lobase + 512);
        f16x4 l3 = *(const f16x4*)(lobase + 768);
#pragma unroll
        for (int i = 0; i < 4; ++i) {
          f16x4 n0, n1, n2, n3;
          if (i + 1 < 4) {
            const hf* nr = lobase + (size_t)(i + 1) * HH;
            n0 = *(const f16x4*)(nr);
            n1 = *(const f16x4*)(nr + 256);
            n2 = *(const f16x4*)(nr + 512);
            n3 = *(const f16x4*)(nr + 768);
          }
          const hf* hrow = o_hi + (size_t)(wv * 4 + i) * HH + lane * 4;
          f16x4 h0 = *(const f16x4*)(hrow);
          f16x4 h1 = *(const f16x4*)(hrow + 256);
          f16x4 h2 = *(const f16x4*)(hrow + 512);
          f16x4 h3 = *(const f16x4*)(hrow + 768);
          float shi = (float)h0[0] * sh0[0] + (float)h0[1] * sh0[1] + (float)h0[2] * sh0[2] + (float)h0[3] * sh0[3]
                    + (float)h1[0] * sh1[0] + (float)h1[1] * sh1[1] + (float)h1[2] * sh1[2] + (float)h1[3] * sh1[3]
                    + (float)h2[0] * sh2[0] + (float)h2[1] * sh2[1] + (float)h2[2] * sh2[2] + (float)h2[3] * sh2[3]
                    + (float)h3[0] * sh3[0] + (float)h3[1] * sh3[1] + (float)h3[2] * sh3[2] + (float)h3[3] * sh3[3];
          float slo = (float)l0[0] * sh0[0] + (float)l0[1] * sh0[1] + (float)l0[2] * sh0[2] + (float)l0[3] * sh0[3]
                    + (float)l1[0] * sh1[0] + (float)l1[1] * sh1[1] + (float)l1[2] * sh1[2] + (float)l1[3] * sh1[3]
                    + (float)l2[0] * sh2[0] + (float)l2[1] * sh2[1] + (float)l2[2] * sh2[2] + (float)l2[3] * sh2[3]
                    + (float)l3[0] * sh3[0] + (float)l3[1] * sh3[1] + (float)l3[2] * sh3[2] + (float)l3[3] * sh3[3];
          float s = shi + slo * (1.0f / 2048.0f);
          for (int off = 32; off; off >>= 1) s += __shfl_xor(s, off);
          if (lane == 0) a.scores[(size_t)b * TE + q * 64 + wv * 4 + i] = s;
          l0 = n0; l1 = n1; l2 = n2; l3 = n3;
        }
      }
      __syncthreads();
      if (tid == 0) {
        __threadfence();
        __hip_atomic_store(&a.afl[b * 4 + q], (unsigned)(t + 1),
                           __ATOMIC_RELEASE, __HIP_MEMORY_SCOPE_AGENT);
        for (int p = 1; p < 4; ++p) {
          unsigned idx = b * 4 + ((q + p) & 3);
          while (__hip_atomic_load(&a.afl[idx], __ATOMIC_RELAXED, __HIP_MEMORY_SCOPE_AGENT)
                 < (unsigned)(t + 1))
            __builtin_amdgcn_s_sleep(1);
        }
        __threadfence();
      }
      __syncthreads();
      float sc = 0.f, p = 0.f;
      if (tid < 256) {
        sc = a.scores[(size_t)b * TE + tid];
        float v = sc;
        for (int off = 32; off; off >>= 1) v = fmaxf(v, __shfl_xor(v, off));
        if (lane == 0) s_red[wv] = v;
      }
      __syncthreads();
      {
        float mx = fmaxf(fmaxf(s_red[0], s_red[1]), fmaxf(s_red[2], s_red[3]));
        if (tid < 256) {
          p = expf(sc - mx);
          float sum = p;
          for (int off = 32; off; off >>= 1) sum += __shfl_xor(sum, off);
          if (lane == 0) s_red[4 + wv] = sum;
        }
      }
      __syncthreads();
      bool act = false;
      unsigned long long bm = 0;
      if (tid < 256) {
        float tot = s_red[4] + s_red[5] + s_red[6] + s_red[7];
        float w2 = p / tot;
        s_sm[tid] = w2;
        act = (w2 > 1e-8f);
        bm = __ballot(act);
        if (lane == 0) s_wcnt[wv] = __popcll(bm);
      }
      __syncthreads();
      if (tid < 256 && act) {
        int base = 0;
        for (int w2i = 0; w2i < wv; ++w2i) base += s_wcnt[w2i];
        int pos = base + __popcll(bm & ((1ULL << lane) - 1));
        s_idx[pos] = tid;
      }
      __syncthreads();
      const int nact = s_wcnt[0] + s_wcnt[1] + s_wcnt[2] + s_wcnt[3];
      // value over compacted list: hi+lo fp16 planes (lo L2-hot), 4-deep chunks
      if (tid < 512) {
        const int c = tid & 255, th = tid >> 8;
        const int j = q * 256 + c;
        const hf* hib = a.ohi + (size_t)b * TE * HH + j;
        const hf* lob = a.olo + (size_t)b * TE * HH + j;
        float accv = 0.f;
        int ii = th;
        for (; ii + 6 < nact; ii += 8) {
          const int i0 = s_idx[ii], i1 = s_idx[ii + 2], i2 = s_idx[ii + 4], i3 = s_idx[ii + 6];
          const float h0 = (float)hib[(size_t)i0 * HH], l0 = (float)lob[(size_t)i0 * HH];
          const float h1 = (float)hib[(size_t)i1 * HH], l1 = (float)lob[(size_t)i1 * HH];
          const float h2 = (float)hib[(size_t)i2 * HH], l2 = (float)lob[(size_t)i2 * HH];
          const float h3 = (float)hib[(size_t)i3 * HH], l3 = (float)lob[(size_t)i3 * HH];
          accv += s_sm[i0] * (h0 + l0 * (1.0f / 2048.0f));
          accv += s_sm[i1] * (h1 + l1 * (1.0f / 2048.0f));
          accv += s_sm[i2] * (h2 + l2 * (1.0f / 2048.0f));
          accv += s_sm[i3] * (h3 + l3 * (1.0f / 2048.0f));
        }
        for (; ii < nact; ii += 2) {
          const int tt2 = s_idx[ii];
          accv += s_sm[tt2] * ((float)hib[(size_t)tt2 * HH] +
                               (float)lob[(size_t)tt2 * HH] * (1.0f / 2048.0f));
        }
        s_val[th * 256 + c] = accv;
      }
      __syncthreads();
      if (tid < 256)
        split3_write(a.vl0, a.vl1, a.vl2, (size_t)b * HH + q * 256 + tid,
                     s_val[tid] + s_val[256 + tid]);
      // publish: this quartet member's vl (and hs for q==0) is complete
      __syncthreads();
      if (tid == 0) {
        __threadfence();
        __hip_atomic_fetch_add(a.vc + b * 32, 1u, __ATOMIC_ACQ_REL, __HIP_MEMORY_SCOPE_AGENT);
      }
    }

    // ---- PH4 entry: wait for the 16 batches this WG consumes (4 members each)
    {
      const int mt = wg >> 6;
      if (tid < 16) {
        const unsigned tgt = 4u * (unsigned)(t + 1);
        unsigned* f = a.vc + (mt * 16 + tid) * 32;
        while (__hip_atomic_load(f, __ATOMIC_RELAXED, __HIP_MEMORY_SCOPE_AGENT) < tgt)
          __builtin_amdgcn_s_sleep(1);
        __threadfence();
      }
      __syncthreads();
    }

    // ===== PH4: att GEMM full-K in-WG; LDS reduce -> out/ifd; stage x_{t+1} =====
    {
      const int cu = wg & 63;
      const int mt = wg >> 6;
      const int kq16 = wv;
      const bool isv = (kq16 < 8);
      const int koff = (kq16 & 7) * 128;
      const bf* A0 = isv ? a.vl0 : a.hs0;
      const bf* A1 = isv ? a.vl1 : a.hs1;
      const bf* A2 = isv ? a.vl2 : a.hs2;
      const size_t aoff = (size_t)(mt * 16 + lrow) * HH + koff + lkg * 8;
      const size_t boff = (size_t)(cu * 16 + lrow) * 2048 + kq16 * 128 + lkg * 8;
      f32x4 acc = gemm6<128>(A0 + aoff, A1 + aoff, A2 + aoff,
                             a.Wa0 + boff, a.Wa1 + boff, a.Wa2 + boff);
#pragma unroll
      for (int r = 0; r < 4; ++r)
        s_u[kq16 * 256 + (lkg * 4 + r) * 16 + lrow] = acc[r];
      __syncthreads();
      if (tid < 256) {
        const int r16 = tid >> 4, c16 = tid & 15;
        const int e = r16 * 16 + c16;
        float v = a.batt[cu * 16 + c16];
#pragma unroll
        for (int kq = 0; kq < 16; ++kq) v += s_u[kq * 256 + e];
        float hv = tanhf(v);
        const int row = mt * 16 + r16;
        const int col = cu * 16 + c16;
        a.out[((size_t)row * TD + t) * HH + col] = hv;
        split3_write(a.ifd0, a.ifd1, a.ifd2, (size_t)row * HH + col, hv);
      }
      if (wg < 64 && t + 1 < TD) {
        split3_write(a.xt0, a.xt1, a.xt2, (size_t)wg * HH + tid,
                     a.x[((size_t)wg * TD + (t + 1)) * HH + tid]);
      }
    }
    gbar(++ep, a, wg);
  }
}

// -------- prep kernels --------
__global__ void k_tr3(const float* src, bf* d0, bf* d1, bf* d2, int R, int C) {
  __shared__ float tile[32][33];
  int c0 = blockIdx.x * 32, r0 = blockIdx.y * 32;
  int tx = threadIdx.x & 31, ty = threadIdx.x >> 5;
  for (int i = ty; i < 32; i += 8)
    tile[i][tx] = src[(size_t)(r0 + i) * C + c0 + tx];
  __syncthreads();
  for (int i = ty; i < 32; i += 8) {
    float v = tile[tx][i];
    size_t o = (size_t)(c0 + i) * R + r0 + tx;
    bf b0 = __float2bfloat16(v);
    float r1 = v - __bfloat162float(b0);
    bf b1 = __float2bfloat16(r1);
    d0[o] = b0; d1[o] = b1; d2[o] = __float2bfloat16(r1 - __bfloat162float(b1));
  }
}

__global__ void k_osplit(const float* src, hf* dhi, hf* dlo) {
  size_t i = (size_t)blockIdx.x * blockDim.x + threadIdx.x;
  float v = src[i];
  hf h = (hf)v;
  dhi[i] = h;
  dlo[i] = (hf)((v - (float)h) * 2048.0f);
}

__global__ void k_init(const float* h_enc, float* h_f32, bf* h0, bf* h1, bf* h2,
                       bf* i0, bf* i1, bf* i2, const float* x, bf* x0, bf* x1, bf* x2) {
  int i = blockIdx.x * blockDim.x + threadIdx.x;
  float v = h_enc[i];
  h_f32[i] = v;
  split3_write(h0, h1, h2, i, v);
  bf z = __float2bfloat16(0.f);
  i0[i] = z; i1[i] = z; i2[i] = z;
  int row = i >> 10, col = i & 1023;
  split3_write(x0, x1, x2, i, x[((size_t)row * TD + 0) * HH + col]);
}

extern "C" void kernel_launch(void* const* d_in, const int* in_sizes, int n_in,
                              void* d_out, int out_size, void* d_ws, size_t ws_size,
                              hipStream_t stream) {
  const float* x     = (const float*)d_in[0];
  const float* o_enc = (const float*)d_in[1];
  const float* h_enc = (const float*)d_in[2];
  const float* Wfeed = (const float*)d_in[3];
  const float* bfeed = (const float*)d_in[4];
  const float* Wx    = (const float*)d_in[5];
  const float* Wh    = (const float*)d_in[6];
  const float* bxi   = (const float*)d_in[7];
  const float* bhr   = (const float*)d_in[8];
  const float* Watt  = (const float*)d_in[9];
  const float* batt  = (const float*)d_in[10];

  char* w = (char*)d_ws;
  auto alloc = [&](size_t b) { char* p = w; w += (b + 255) & ~255ULL; return p; };

  const size_t M1 = (size_t)1024 * 1024 * 2;
  bf* Wf[3];  for (auto& p : Wf)  p = (bf*)alloc(M1);
  bf* Wh_[3]; for (auto& p : Wh_) p = (bf*)alloc(3 * M1);
  bf* WxF[3]; for (auto& p : WxF) p = (bf*)alloc(3 * M1);
  bf* WxX[3]; for (auto& p : WxX) p = (bf*)alloc(3 * M1);
  bf* Wa[3];  for (auto& p : Wa)  p = (bf*)alloc(2 * M1);
  hf* ohi = (hf*)alloc((size_t)BB * TE * HH * 2);
  hf* olo = (hf*)alloc((size_t)BB * TE * HH * 2);
  float* h_f32  = (float*)alloc((size_t)2 * BB * HH * 4);
  float* gx     = (float*)alloc((size_t)BB * H3 * 4);
  float* gh     = (float*)alloc((size_t)BB * H3 * 4);
  float* scores = (float*)alloc((size_t)BB * TE * 4);
  const size_t AB = (size_t)BB * HH * 2;
  bf *hs[3], *ff[3], *ifd[3], *xt[3], *vl[3];
  for (auto& p : hs)  p = (bf*)alloc(AB);
  for (auto& p : ff)  p = (bf*)alloc(AB);
  for (auto& p : ifd) p = (bf*)alloc(AB);
  for (auto& p : xt)  p = (bf*)alloc(AB);
  for (auto& p : vl)  p = (bf*)alloc(AB);
  unsigned* flags = (unsigned*)alloc(16384);

  hipMemsetAsync(flags, 0, 16384, stream);
  k_tr3<<<dim3(32, 32), 256, 0, stream>>>(Wfeed, Wf[0], Wf[1], Wf[2], 1024, 1024);
  k_tr3<<<dim3(96, 32), 256, 0, stream>>>(Wx, WxF[0], WxF[1], WxF[2], 1024, 3072);
  k_tr3<<<dim3(96, 32), 256, 0, stream>>>(Wx + (size_t)1024 * 3072, WxX[0], WxX[1], WxX[2], 1024, 3072);
  k_tr3<<<dim3(96, 32), 256, 0, stream>>>(Wh, Wh_[0], Wh_[1], Wh_[2], 1024, 3072);
  k_tr3<<<dim3(32, 64), 256, 0, stream>>>(Watt, Wa[0], Wa[1], Wa[2], 2048, 1024);
  k_osplit<<<(BB * TE * HH) / 256, 256, 0, stream>>>(o_enc, ohi, olo);
  k_init<<<BB * HH / 256, 256, 0, stream>>>(h_enc, h_f32, hs[0], hs[1], hs[2],
                                            ifd[0], ifd[1], ifd[2], x, xt[0], xt[1], xt[2]);

  Args a;
  a.x = x; a.bfeed = bfeed; a.bxi = bxi; a.bhr = bhr; a.batt = batt;
  a.ohi = ohi; a.olo = olo;
  a.Wf0 = Wf[0]; a.Wf1 = Wf[1]; a.Wf2 = Wf[2];
  a.Wh0 = Wh_[0]; a.Wh1 = Wh_[1]; a.Wh2 = Wh_[2];
  a.WxF0 = WxF[0]; a.WxF1 = WxF[1]; a.WxF2 = WxF[2];
  a.WxX0 = WxX[0]; a.WxX1 = WxX[1]; a.WxX2 = WxX[2];
  a.Wa0 = Wa[0]; a.Wa1 = Wa[1]; a.Wa2 = Wa[2];
  a.h_f32 = h_f32; a.gx = gx; a.gh = gh; a.scores = scores;
  a.hs0 = hs[0]; a.hs1 = hs[1]; a.hs2 = hs[2];
  a.ff0 = ff[0]; a.ff1 = ff[1]; a.ff2 = ff[2];
  a.ifd0 = ifd[0]; a.ifd1 = ifd[1]; a.ifd2 = ifd[2];
  a.xt0 = xt[0]; a.xt1 = xt[1]; a.xt2 = xt[2];
  a.vl0 = vl[0]; a.vl1 = vl[1]; a.vl2 = vl[2];
  a.cnt = flags; a.cnt2 = flags + 512; a.go = flags + 544; a.afl = flags + 576;
  a.gox = flags + 832; a.ffc = flags + 1088; a.ffx = flags + 1120;
  a.vc = flags + 1408;   // 64 batches x 32-stride counters
  a.out = (float*)d_out;

  hipFuncSetAttribute((const void*)decoder_main,
                      hipFuncAttributeMaxDynamicSharedMemorySize, SMEM_BYTES);
  decoder_main<<<NWG, NTHR, SMEM_BYTES, stream>>>(a);
}

// Round 18
// 20947.862 us; speedup vs baseline: 1.0818x; 1.0198x over previous
//
#include <hip/hip_runtime.h>
#include <hip/hip_bf16.h>
#include <hip/hip_fp16.h>

// Decoder: 128-step GRU + Luong attention, B=64, H=1024. Persistent kernel,
// 256 WGs x 1024 thr, 3 grid barriers/step + producer-counter, 4 phases.
// NUMERICS: weights bf16 3-way splits + 6-pass MFMA (2^-27, frozen); fp32
// state; o_enc as fp16 hi (LDS-resident) + fp16 lo*2048 streamed (2^-22).
// ROUND 18 = ROUND 15 VERBATIM (best measured: 21.14 ms, absmax 0.01367,
// FETCH 11.1 GB). r16 (value restructure) and r17 (PH3->PH4 producer flags)
// both regressed or nulled; this locks in the best configuration.

#define NWG 256
#define NTHR 1024
constexpr int BB = 64, TD = 128, TE = 256, HH = 1024, H3 = 3072;
constexpr unsigned SMEM_BYTES = 155696;

typedef __attribute__((ext_vector_type(8))) __bf16 bf16x8;
typedef __attribute__((ext_vector_type(4))) float f32x4;
typedef __attribute__((ext_vector_type(4))) _Float16 f16x4;
using bf = __hip_bfloat16;
using hf = _Float16;

__device__ __forceinline__ f32x4 mfma16(bf16x8 a, bf16x8 b, f32x4 c) {
  return __builtin_amdgcn_mfma_f32_16x16x32_bf16(a, b, c, 0, 0, 0);
}

struct Args {
  const float *x, *bfeed, *bxi, *bhr, *batt;
  const hf *ohi, *olo;
  const bf *Wf0, *Wf1, *Wf2, *Wh0, *Wh1, *Wh2;
  const bf *WxF0, *WxF1, *WxF2, *WxX0, *WxX1, *WxX2, *Wa0, *Wa1, *Wa2;
  float *h_f32;          // 2 planes ping-pong
  float *gx;             // 64 x 3072
  float *gh, *scores;
  bf *hs0, *hs1, *hs2, *ff0, *ff1, *ff2, *ifd0, *ifd1, *ifd2;
  bf *xt0, *xt1, *xt2, *vl0, *vl1, *vl2;
  unsigned *cnt, *cnt2, *go, *afl, *gox, *ffc, *ffx;
  float *out;
};

// Hierarchical grid barrier (r14): 2-level arrive; release root->8 XCD lines.
__device__ __forceinline__ void gbar(unsigned ep, const Args& a, int wg) {
  __syncthreads();
  if (threadIdx.x == 0) {
    __threadfence();
    unsigned* sub = a.cnt + (wg & 15) * 32;
    unsigned o = __hip_atomic_fetch_add(sub, 1u, __ATOMIC_ACQ_REL, __HIP_MEMORY_SCOPE_AGENT);
    if (o == 15) {
      __hip_atomic_store(sub, 0u, __ATOMIC_RELAXED, __HIP_MEMORY_SCOPE_AGENT);
      unsigned o2 = __hip_atomic_fetch_add(a.cnt2, 1u, __ATOMIC_ACQ_REL, __HIP_MEMORY_SCOPE_AGENT);
      if (o2 == 15) {
        __hip_atomic_store(a.cnt2, 0u, __ATOMIC_RELAXED, __HIP_MEMORY_SCOPE_AGENT);
        __hip_atomic_store(a.go, ep, __ATOMIC_RELEASE, __HIP_MEMORY_SCOPE_AGENT);
      }
    }
    if (wg < 8) {
      while (__hip_atomic_load(a.go, __ATOMIC_RELAXED, __HIP_MEMORY_SCOPE_AGENT) < ep)
        __builtin_amdgcn_s_sleep(1);
      __hip_atomic_store(a.gox + wg * 32, ep, __ATOMIC_RELEASE, __HIP_MEMORY_SCOPE_AGENT);
    } else {
      while (__hip_atomic_load(a.gox + (wg & 7) * 32, __ATOMIC_RELAXED,
                               __HIP_MEMORY_SCOPE_AGENT) < ep)
        __builtin_amdgcn_s_sleep(1);
    }
    __threadfence();
  }
  __syncthreads();
}

__device__ __forceinline__ void split3_write(bf* p0, bf* p1, bf* p2, size_t i, float v) {
  bf b0 = __float2bfloat16(v);
  float r1 = v - __bfloat162float(b0);
  bf b1 = __float2bfloat16(r1);
  float r2 = r1 - __bfloat162float(b1);
  p0[i] = b0; p1[i] = b1; p2[i] = __float2bfloat16(r2);
}

// 2-stage register-pipelined 6-pass split GEMM (r13; MFMA order = proven gemm6).
template <int K>
__device__ __forceinline__ f32x4 gemm6(const bf* A0, const bf* A1, const bf* A2,
                                       const bf* B0, const bf* B1, const bf* B2) {
  f32x4 c0 = {0.f, 0.f, 0.f, 0.f}, c1 = c0, c2 = c0, c3 = c0;
  bf16x8 a0 = *(const bf16x8*)(A0);
  bf16x8 a1 = *(const bf16x8*)(A1);
  bf16x8 a2 = *(const bf16x8*)(A2);
  bf16x8 b0 = *(const bf16x8*)(B0);
  bf16x8 b1 = *(const bf16x8*)(B1);
  bf16x8 b2 = *(const bf16x8*)(B2);
#pragma unroll
  for (int k = 0; k < K; k += 32) {
    bf16x8 na0, na1, na2, nb0, nb1, nb2;
    if (k + 32 < K) {
      na0 = *(const bf16x8*)(A0 + k + 32);
      na1 = *(const bf16x8*)(A1 + k + 32);
      na2 = *(const bf16x8*)(A2 + k + 32);
      nb0 = *(const bf16x8*)(B0 + k + 32);
      nb1 = *(const bf16x8*)(B1 + k + 32);
      nb2 = *(const bf16x8*)(B2 + k + 32);
    }
    c0 = mfma16(a0, b0, c0);
    c1 = mfma16(a0, b1, c1);
    c2 = mfma16(a1, b0, c2);
    c3 = mfma16(a1, b1, c3);
    c0 = mfma16(a0, b2, c0);
    c1 = mfma16(a2, b0, c1);
    if (k + 32 < K) {
      a0 = na0; a1 = na1; a2 = na2;
      b0 = nb0; b1 = nb1; b2 = nb2;
    }
  }
  f32x4 s;
#pragma unroll
  for (int i = 0; i < 4; ++i) s[i] = (c0[i] + c1[i]) + (c2[i] + c3[i]);
  return s;
}

__global__ __launch_bounds__(NTHR, 4) void decoder_main(Args a) {
  const int wg = blockIdx.x;
  const int tid = threadIdx.x;
  const int lane = tid & 63;
  const int wv = tid >> 6;       // wave 0..15
  const int lrow = lane & 15;
  const int lkg = lane >> 4;

  extern __shared__ char smem[];
  hf* o_hi     = (hf*)smem;                    // [64][1024] fp16 = 131072 B
  float* s_u   = (float*)(smem + 131072);      // 4096 f
  float* s_h   = (float*)(smem + 147456);      // 1024 f
  float* s_sm  = (float*)(smem + 151552);      // 256 f
  float* s_val = (float*)(smem + 152576);      // [2][256] f
  int* s_idx   = (int*)(smem + 154624);        // 256 i
  int* s_wcnt  = (int*)(smem + 155648);        // 4 i
  float* s_red = (float*)(smem + 155664);      // 8 f

  const int b3 = wg & 63, q3 = wg >> 6;   // PH3 identity (fixed all steps)
  // Prolog: load this WG's 64 score rows' hi-plane into LDS (once).
  {
    const ushort* src = (const ushort*)(a.ohi + ((size_t)b3 * TE + q3 * 64) * HH);
    ushort* dst = (ushort*)o_hi;
#pragma unroll 4
    for (int i = tid; i < 16384; i += NTHR)
      ((ushort4*)dst)[i] = ((const ushort4*)src)[i];
  }

  unsigned ep = 0;

  for (int t = 0; t < TD; ++t) {
    // ===== Phase I: ffeed (WGs 0..63) || gh (WGs 64..255); producer counter =====
    {
      const bool isf = (wg < 64);
      const int j0 = (isf ? wg : wg - 64) * 16;
      const bf* A0 = isf ? a.ifd0 : a.hs0;
      const bf* A1 = isf ? a.ifd1 : a.hs1;
      const bf* A2 = isf ? a.ifd2 : a.hs2;
      const bf* B0 = isf ? a.Wf0 : a.Wh0;
      const bf* B1 = isf ? a.Wf1 : a.Wh1;
      const bf* B2 = isf ? a.Wf2 : a.Wh2;
      const int mt = wv >> 2, kq = wv & 3;
      const size_t aoff = (size_t)(mt * 16 + lrow) * HH + kq * 256 + lkg * 8;
      const size_t boff = (size_t)(j0 + lrow) * HH + kq * 256 + lkg * 8;
      f32x4 acc = gemm6<256>(A0 + aoff, A1 + aoff, A2 + aoff, B0 + boff, B1 + boff, B2 + boff);
#pragma unroll
      for (int r = 0; r < 4; ++r) s_u[kq * 1024 + mt * 256 + (lkg * 4 + r) * 16 + lrow] = acc[r];
      __syncthreads();
      {
        const int row = tid >> 4, c = tid & 15;
        const int emt = row >> 4, r2 = row & 15;
        const int e = emt * 256 + r2 * 16 + c;
        float v = (s_u[e] + s_u[1024 + e]) + (s_u[2048 + e] + s_u[3072 + e]);
        const int col = j0 + c;
        if (isf) {
          float f = tanhf(v + a.bfeed[col]);
          split3_write(a.ff0, a.ff1, a.ff2, (size_t)row * HH + col, f);
        } else {
          a.gh[(size_t)row * H3 + col] = v + a.bhr[col];
        }
      }
      __syncthreads();
      if (isf && tid == 0) {
        __threadfence();
        __hip_atomic_fetch_add(a.ffc, 1u, __ATOMIC_ACQ_REL, __HIP_MEMORY_SCOPE_AGENT);
      }
    }
    if (tid == 0) {
      const unsigned tgt = 64u * (unsigned)(t + 1);
      if (wg < 8) {
        while (__hip_atomic_load(a.ffc, __ATOMIC_RELAXED, __HIP_MEMORY_SCOPE_AGENT) < tgt)
          __builtin_amdgcn_s_sleep(1);
        __hip_atomic_store(a.ffx + wg * 32, tgt, __ATOMIC_RELEASE, __HIP_MEMORY_SCOPE_AGENT);
      } else {
        while (__hip_atomic_load(a.ffx + (wg & 7) * 32, __ATOMIC_RELAXED,
                                 __HIP_MEMORY_SCOPE_AGENT) < tgt)
          __builtin_amdgcn_s_sleep(1);
      }
      __threadfence();
    }
    __syncthreads();

    // ===== Phase II: gx; r12 layout (XCD-aware (jt,sub), 12 waves) =====
    {
      const int xcd = wg & 7, slot = wg >> 3;
      const int jt = xcd * 8 + (slot >> 2), sub = slot & 3;
      if (wv < 12) {
        const int ci = wv >> 2, ku = wv & 3;
        const int c2 = sub * 3 + ci;
        const int g = c2 >> 2, mt = c2 & 3;
        const int op = ku >> 1, kh = ku & 1;
        const bf* A0 = op ? a.xt0 : a.ff0;
        const bf* A1 = op ? a.xt1 : a.ff1;
        const bf* A2 = op ? a.xt2 : a.ff2;
        const bf* B0 = op ? a.WxX0 : a.WxF0;
        const bf* B1 = op ? a.WxX1 : a.WxF1;
        const bf* B2 = op ? a.WxX2 : a.WxF2;
        const size_t aoff = (size_t)(mt * 16 + lrow) * HH + kh * 512 + lkg * 8;
        const size_t boff = (size_t)(g * HH + jt * 16 + lrow) * HH + kh * 512 + lkg * 8;
        f32x4 acc = gemm6<512>(A0 + aoff, A1 + aoff, A2 + aoff, B0 + boff, B1 + boff, B2 + boff);
#pragma unroll
        for (int r = 0; r < 4; ++r)
          s_u[ci * 1024 + ku * 256 + (lkg * 4 + r) * 16 + lrow] = acc[r];
      }
      __syncthreads();
      if (tid < 768) {
        const int ci2 = tid >> 8, e = tid & 255;
        const int r16 = e >> 4, c16 = e & 15;
        const int base = ci2 * 1024 + e;
        float v = (s_u[base] + s_u[base + 256]) + (s_u[base + 512] + s_u[base + 768]);
        const int c2 = sub * 3 + ci2;
        const int g = c2 >> 2, mt = c2 & 3;
        a.gx[(size_t)(mt * 16 + r16) * H3 + g * 1024 + jt * 16 + c16] = v;
      }
    }
    gbar(++ep, a, wg);

    // ===== PH3: GRU pointwise + scores (LDS hi + streamed lo) + softmax + value =====
    {
      const int b = b3, q = q3;
      const float* hold = a.h_f32 + (size_t)(t & 1) * (BB * HH);
      float* hnew = a.h_f32 + (size_t)((t + 1) & 1) * (BB * HH);
      const float* ghb = a.gh + (size_t)b * H3;
      {
        const int col = tid;
        const float* gxb = a.gx + (size_t)b * H3;
        float gz = a.bxi[col] + gxb[col];
        float gr = a.bxi[HH + col] + gxb[HH + col];
        float gc = a.bxi[2 * HH + col] + gxb[2 * HH + col];
        float z = 1.f / (1.f + expf(-(gz + ghb[col])));
        float rr = 1.f / (1.f + expf(-(gr + ghb[HH + col])));
        float hc = tanhf(gc + rr * ghb[2 * HH + col]);
        float hn = z * hold[(size_t)b * HH + col] + (1.f - z) * hc;
        s_h[col] = hn;
        if (q == 0) {
          hnew[(size_t)b * HH + col] = hn;
          split3_write(a.hs0, a.hs1, a.hs2, (size_t)b * HH + col, hn);
        }
      }
      __syncthreads();
      // scores: hi from LDS, lo streamed (2-deep pipelined); 16 waves x 4 rows
      {
        f32x4 sh0 = *(const f32x4*)(s_h + 0 + lane * 4);
        f32x4 sh1 = *(const f32x4*)(s_h + 256 + lane * 4);
        f32x4 sh2 = *(const f32x4*)(s_h + 512 + lane * 4);
        f32x4 sh3 = *(const f32x4*)(s_h + 768 + lane * 4);
        const hf* lobase = a.olo + ((size_t)b * TE + q * 64 + wv * 4) * HH + lane * 4;
        f16x4 l0 = *(const f16x4*)(lobase);
        f16x4 l1 = *(const f16x4*)(lobase + 256);
        f16x4 l2 = *(const f16x4*)(lobase + 512);
        f16x4 l3 = *(const f16x4*)(lobase + 768);
#pragma unroll
        for (int i = 0; i < 4; ++i) {
          f16x4 n0, n1, n2, n3;
          if (i + 1 < 4) {
            const hf* nr = lobase + (size_t)(i + 1) * HH;
            n0 = *(const f16x4*)(nr);
            n1 = *(const f16x4*)(nr + 256);
            n2 = *(const f16x4*)(nr + 512);
            n3 = *(const f16x4*)(nr + 768);
          }
          const hf* hrow = o_hi + (size_t)(wv * 4 + i) * HH + lane * 4;
          f16x4 h0 = *(const f16x4*)(hrow);
          f16x4 h1 = *(const f16x4*)(hrow + 256);
          f16x4 h2 = *(const f16x4*)(hrow + 512);
          f16x4 h3 = *(const f16x4*)(hrow + 768);
          float shi = (float)h0[0] * sh0[0] + (float)h0[1] * sh0[1] + (float)h0[2] * sh0[2] + (float)h0[3] * sh0[3]
                    + (float)h1[0] * sh1[0] + (float)h1[1] * sh1[1] + (float)h1[2] * sh1[2] + (float)h1[3] * sh1[3]
                    + (float)h2[0] * sh2[0] + (float)h2[1] * sh2[1] + (float)h2[2] * sh2[2] + (float)h2[3] * sh2[3]
                    + (float)h3[0] * sh3[0] + (float)h3[1] * sh3[1] + (float)h3[2] * sh3[2] + (float)h3[3] * sh3[3];
          float slo = (float)l0[0] * sh0[0] + (float)l0[1] * sh0[1] + (float)l0[2] * sh0[2] + (float)l0[3] * sh0[3]
                    + (float)l1[0] * sh1[0] + (float)l1[1] * sh1[1] + (float)l1[2] * sh1[2] + (float)l1[3] * sh1[3]
                    + (float)l2[0] * sh2[0] + (float)l2[1] * sh2[1] + (float)l2[2] * sh2[2] + (float)l2[3] * sh2[3]
                    + (float)l3[0] * sh3[0] + (float)l3[1] * sh3[1] + (float)l3[2] * sh3[2] + (float)l3[3] * sh3[3];
          float s = shi + slo * (1.0f / 2048.0f);
          for (int off = 32; off; off >>= 1) s += __shfl_xor(s, off);
          if (lane == 0) a.scores[(size_t)b * TE + q * 64 + wv * 4 + i] = s;
          l0 = n0; l1 = n1; l2 = n2; l3 = n3;
        }
      }
      __syncthreads();
      if (tid == 0) {
        __threadfence();
        __hip_atomic_store(&a.afl[b * 4 + q], (unsigned)(t + 1),
                           __ATOMIC_RELEASE, __HIP_MEMORY_SCOPE_AGENT);
        for (int p = 1; p < 4; ++p) {
          unsigned idx = b * 4 + ((q + p) & 3);
          while (__hip_atomic_load(&a.afl[idx], __ATOMIC_RELAXED, __HIP_MEMORY_SCOPE_AGENT)
                 < (unsigned)(t + 1))
            __builtin_amdgcn_s_sleep(1);
        }
        __threadfence();
      }
      __syncthreads();
      float sc = 0.f, p = 0.f;
      if (tid < 256) {
        sc = a.scores[(size_t)b * TE + tid];
        float v = sc;
        for (int off = 32; off; off >>= 1) v = fmaxf(v, __shfl_xor(v, off));
        if (lane == 0) s_red[wv] = v;
      }
      __syncthreads();
      {
        float mx = fmaxf(fmaxf(s_red[0], s_red[1]), fmaxf(s_red[2], s_red[3]));
        if (tid < 256) {
          p = expf(sc - mx);
          float sum = p;
          for (int off = 32; off; off >>= 1) sum += __shfl_xor(sum, off);
          if (lane == 0) s_red[4 + wv] = sum;
        }
      }
      __syncthreads();
      bool act = false;
      unsigned long long bm = 0;
      if (tid < 256) {
        float tot = s_red[4] + s_red[5] + s_red[6] + s_red[7];
        float w2 = p / tot;
        s_sm[tid] = w2;
        act = (w2 > 1e-8f);
        bm = __ballot(act);
        if (lane == 0) s_wcnt[wv] = __popcll(bm);
      }
      __syncthreads();
      if (tid < 256 && act) {
        int base = 0;
        for (int w2i = 0; w2i < wv; ++w2i) base += s_wcnt[w2i];
        int pos = base + __popcll(bm & ((1ULL << lane) - 1));
        s_idx[pos] = tid;
      }
      __syncthreads();
      const int nact = s_wcnt[0] + s_wcnt[1] + s_wcnt[2] + s_wcnt[3];
      // value over compacted list: hi+lo fp16 planes (lo L2-hot), 4-deep chunks
      if (tid < 512) {
        const int c = tid & 255, th = tid >> 8;
        const int j = q * 256 + c;
        const hf* hib = a.ohi + (size_t)b * TE * HH + j;
        const hf* lob = a.olo + (size_t)b * TE * HH + j;
        float accv = 0.f;
        int ii = th;
        for (; ii + 6 < nact; ii += 8) {
          const int i0 = s_idx[ii], i1 = s_idx[ii + 2], i2 = s_idx[ii + 4], i3 = s_idx[ii + 6];
          const float h0 = (float)hib[(size_t)i0 * HH], l0 = (float)lob[(size_t)i0 * HH];
          const float h1 = (float)hib[(size_t)i1 * HH], l1 = (float)lob[(size_t)i1 * HH];
          const float h2 = (float)hib[(size_t)i2 * HH], l2 = (float)lob[(size_t)i2 * HH];
          const float h3 = (float)hib[(size_t)i3 * HH], l3 = (float)lob[(size_t)i3 * HH];
          accv += s_sm[i0] * (h0 + l0 * (1.0f / 2048.0f));
          accv += s_sm[i1] * (h1 + l1 * (1.0f / 2048.0f));
          accv += s_sm[i2] * (h2 + l2 * (1.0f / 2048.0f));
          accv += s_sm[i3] * (h3 + l3 * (1.0f / 2048.0f));
        }
        for (; ii < nact; ii += 2) {
          const int tt2 = s_idx[ii];
          accv += s_sm[tt2] * ((float)hib[(size_t)tt2 * HH] +
                               (float)lob[(size_t)tt2 * HH] * (1.0f / 2048.0f));
        }
        s_val[th * 256 + c] = accv;
      }
      __syncthreads();
      if (tid < 256)
        split3_write(a.vl0, a.vl1, a.vl2, (size_t)b * HH + q * 256 + tid,
                     s_val[tid] + s_val[256 + tid]);
    }
    gbar(++ep, a, wg);

    // ===== PH4: att GEMM full-K in-WG; LDS reduce -> out/ifd; stage x_{t+1} =====
    {
      const int cu = wg & 63;
      const int mt = wg >> 6;
      const int kq16 = wv;
      const bool isv = (kq16 < 8);
      const int koff = (kq16 & 7) * 128;
      const bf* A0 = isv ? a.vl0 : a.hs0;
      const bf* A1 = isv ? a.vl1 : a.hs1;
      const bf* A2 = isv ? a.vl2 : a.hs2;
      const size_t aoff = (size_t)(mt * 16 + lrow) * HH + koff + lkg * 8;
      const size_t boff = (size_t)(cu * 16 + lrow) * 2048 + kq16 * 128 + lkg * 8;
      f32x4 acc = gemm6<128>(A0 + aoff, A1 + aoff, A2 + aoff,
                             a.Wa0 + boff, a.Wa1 + boff, a.Wa2 + boff);
#pragma unroll
      for (int r = 0; r < 4; ++r)
        s_u[kq16 * 256 + (lkg * 4 + r) * 16 + lrow] = acc[r];
      __syncthreads();
      if (tid < 256) {
        const int r16 = tid >> 4, c16 = tid & 15;
        const int e = r16 * 16 + c16;
        float v = a.batt[cu * 16 + c16];
#pragma unroll
        for (int kq = 0; kq < 16; ++kq) v += s_u[kq * 256 + e];
        float hv = tanhf(v);
        const int row = mt * 16 + r16;
        const int col = cu * 16 + c16;
        a.out[((size_t)row * TD + t) * HH + col] = hv;
        split3_write(a.ifd0, a.ifd1, a.ifd2, (size_t)row * HH + col, hv);
      }
      if (wg < 64 && t + 1 < TD) {
        split3_write(a.xt0, a.xt1, a.xt2, (size_t)wg * HH + tid,
                     a.x[((size_t)wg * TD + (t + 1)) * HH + tid]);
      }
    }
    gbar(++ep, a, wg);
  }
}

// -------- prep kernels --------
__global__ void k_tr3(const float* src, bf* d0, bf* d1, bf* d2, int R, int C) {
  __shared__ float tile[32][33];
  int c0 = blockIdx.x * 32, r0 = blockIdx.y * 32;
  int tx = threadIdx.x & 31, ty = threadIdx.x >> 5;
  for (int i = ty; i < 32; i += 8)
    tile[i][tx] = src[(size_t)(r0 + i) * C + c0 + tx];
  __syncthreads();
  for (int i = ty; i < 32; i += 8) {
    float v = tile[tx][i];
    size_t o = (size_t)(c0 + i) * R + r0 + tx;
    bf b0 = __float2bfloat16(v);
    float r1 = v - __bfloat162float(b0);
    bf b1 = __float2bfloat16(r1);
    d0[o] = b0; d1[o] = b1; d2[o] = __float2bfloat16(r1 - __bfloat162float(b1));
  }
}

__global__ void k_osplit(const float* src, hf* dhi, hf* dlo) {
  size_t i = (size_t)blockIdx.x * blockDim.x + threadIdx.x;
  float v = src[i];
  hf h = (hf)v;
  dhi[i] = h;
  dlo[i] = (hf)((v - (float)h) * 2048.0f);
}

__global__ void k_init(const float* h_enc, float* h_f32, bf* h0, bf* h1, bf* h2,
                       bf* i0, bf* i1, bf* i2, const float* x, bf* x0, bf* x1, bf* x2) {
  int i = blockIdx.x * blockDim.x + threadIdx.x;
  float v = h_enc[i];
  h_f32[i] = v;
  split3_write(h0, h1, h2, i, v);
  bf z = __float2bfloat16(0.f);
  i0[i] = z; i1[i] = z; i2[i] = z;
  int row = i >> 10, col = i & 1023;
  split3_write(x0, x1, x2, i, x[((size_t)row * TD + 0) * HH + col]);
}

extern "C" void kernel_launch(void* const* d_in, const int* in_sizes, int n_in,
                              void* d_out, int out_size, void* d_ws, size_t ws_size,
                              hipStream_t stream) {
  const float* x     = (const float*)d_in[0];
  const float* o_enc = (const float*)d_in[1];
  const float* h_enc = (const float*)d_in[2];
  const float* Wfeed = (const float*)d_in[3];
  const float* bfeed = (const float*)d_in[4];
  const float* Wx    = (const float*)d_in[5];
  const float* Wh    = (const float*)d_in[6];
  const float* bxi   = (const float*)d_in[7];
  const float* bhr   = (const float*)d_in[8];
  const float* Watt  = (const float*)d_in[9];
  const float* batt  = (const float*)d_in[10];

  char* w = (char*)d_ws;
  auto alloc = [&](size_t b) { char* p = w; w += (b + 255) & ~255ULL; return p; };

  const size_t M1 = (size_t)1024 * 1024 * 2;
  bf* Wf[3];  for (auto& p : Wf)  p = (bf*)alloc(M1);
  bf* Wh_[3]; for (auto& p : Wh_) p = (bf*)alloc(3 * M1);
  bf* WxF[3]; for (auto& p : WxF) p = (bf*)alloc(3 * M1);
  bf* WxX[3]; for (auto& p : WxX) p = (bf*)alloc(3 * M1);
  bf* Wa[3];  for (auto& p : Wa)  p = (bf*)alloc(2 * M1);
  hf* ohi = (hf*)alloc((size_t)BB * TE * HH * 2);
  hf* olo = (hf*)alloc((size_t)BB * TE * HH * 2);
  float* h_f32  = (float*)alloc((size_t)2 * BB * HH * 4);
  float* gx     = (float*)alloc((size_t)BB * H3 * 4);
  float* gh     = (float*)alloc((size_t)BB * H3 * 4);
  float* scores = (float*)alloc((size_t)BB * TE * 4);
  const size_t AB = (size_t)BB * HH * 2;
  bf *hs[3], *ff[3], *ifd[3], *xt[3], *vl[3];
  for (auto& p : hs)  p = (bf*)alloc(AB);
  for (auto& p : ff)  p = (bf*)alloc(AB);
  for (auto& p : ifd) p = (bf*)alloc(AB);
  for (auto& p : xt)  p = (bf*)alloc(AB);
  for (auto& p : vl)  p = (bf*)alloc(AB);
  unsigned* flags = (unsigned*)alloc(8192);

  hipMemsetAsync(flags, 0, 8192, stream);
  k_tr3<<<dim3(32, 32), 256, 0, stream>>>(Wfeed, Wf[0], Wf[1], Wf[2], 1024, 1024);
  k_tr3<<<dim3(96, 32), 256, 0, stream>>>(Wx, WxF[0], WxF[1], WxF[2], 1024, 3072);
  k_tr3<<<dim3(96, 32), 256, 0, stream>>>(Wx + (size_t)1024 * 3072, WxX[0], WxX[1], WxX[2], 1024, 3072);
  k_tr3<<<dim3(96, 32), 256, 0, stream>>>(Wh, Wh_[0], Wh_[1], Wh_[2], 1024, 3072);
  k_tr3<<<dim3(32, 64), 256, 0, stream>>>(Watt, Wa[0], Wa[1], Wa[2], 2048, 1024);
  k_osplit<<<(BB * TE * HH) / 256, 256, 0, stream>>>(o_enc, ohi, olo);
  k_init<<<BB * HH / 256, 256, 0, stream>>>(h_enc, h_f32, hs[0], hs[1], hs[2],
                                            ifd[0], ifd[1], ifd[2], x, xt[0], xt[1], xt[2]);

  Args a;
  a.x = x; a.bfeed = bfeed; a.bxi = bxi; a.bhr = bhr; a.batt = batt;
  a.ohi = ohi; a.olo = olo;
  a.Wf0 = Wf[0]; a.Wf1 = Wf[1]; a.Wf2 = Wf[2];
  a.Wh0 = Wh_[0]; a.Wh1 = Wh_[1]; a.Wh2 = Wh_[2];
  a.WxF0 = WxF[0]; a.WxF1 = WxF[1]; a.WxF2 = WxF[2];
  a.WxX0 = WxX[0]; a.WxX1 = WxX[1]; a.WxX2 = WxX[2];
  a.Wa0 = Wa[0]; a.Wa1 = Wa[1]; a.Wa2 = Wa[2];
  a.h_f32 = h_f32; a.gx = gx; a.gh = gh; a.scores = scores;
  a.hs0 = hs[0]; a.hs1 = hs[1]; a.hs2 = hs[2];
  a.ff0 = ff[0]; a.ff1 = ff[1]; a.ff2 = ff[2];
  a.ifd0 = ifd[0]; a.ifd1 = ifd[1]; a.ifd2 = ifd[2];
  a.xt0 = xt[0]; a.xt1 = xt[1]; a.xt2 = xt[2];
  a.vl0 = vl[0]; a.vl1 = vl[1]; a.vl2 = vl[2];
  a.cnt = flags; a.cnt2 = flags + 512; a.go = flags + 544; a.afl = flags + 576;
  a.gox = flags + 832; a.ffc = flags + 1088; a.ffx = flags + 1120;
  a.out = (float*)d_out;

  hipFuncSetAttribute((const void*)decoder_main,
                      hipFuncAttributeMaxDynamicSharedMemorySize, SMEM_BYTES);
  decoder_main<<<NWG, NTHR, SMEM_BYTES, stream>>>(a);
}